// Round 1
// baseline (301.181 us; speedup 1.0000x reference)
//
#include <hip/hip_runtime.h>
#include <stdint.h>
#include <math.h>

// Problem constants (fixed by setup_inputs): pred_out [8,5,768,768] f32,
// target_mask [8,1,768,768] i32 (values 0..3), num_target_classes=4 (device scalar).
#define B_ 8
#define C_ 5
#define H_ 768
#define W_ 768
#define HW_ (H_*W_)
#define NPIX (B_*HW_)          // 4,718,592
#define TB 8                   // target bins (>= num_target_classes, clamped)
#define INVAL 0xFFFFFFFFu
#define FIX 16777216.0         // 2^24 fixed-point scale for block-partial sums

struct Acc {
  long long f_logpc[TB][C_];   // sum log(clip(pred)) per (target, predclass>=1)
  long long f_log1m[TB][C_];   // sum log1p(-clip(pred))
  long long f_pred [TB][C_];   // sum pred (raw, for dice)
  unsigned  cnt[TB][C_];       // pixel counts per (target, predclass)
  unsigned  ncomp[8];          // [c-1] = #4-connected components of predclass c
};

// ---------------- union-find (lock-free, device scope) ----------------
static __device__ __forceinline__ unsigned pload(const unsigned* P, unsigned i) {
  return __hip_atomic_load(&P[i], __ATOMIC_RELAXED, __HIP_MEMORY_SCOPE_AGENT);
}
static __device__ unsigned findRoot(const unsigned* P, unsigned i) {
  unsigned p = pload(P, i);
  while (p != i) { i = p; p = pload(P, i); }
  return i;
}
static __device__ void unite(unsigned* P, unsigned a, unsigned b) {
  a = findRoot(P, a);
  b = findRoot(P, b);
  while (a != b) {
    if (a < b) { unsigned t = a; a = b; b = t; }     // link larger index -> smaller
    unsigned old = atomicCAS(&P[a], a, b);
    if (old == a) return;
    a = findRoot(P, old);
    b = findRoot(P, b);
  }
}

// ---------------- kernels ----------------
__global__ void k_zero(Acc* acc) {
  unsigned* p = (unsigned*)acc;
  int n = (int)(sizeof(Acc) / sizeof(unsigned));
  for (int i = threadIdx.x; i < n; i += blockDim.x) p[i] = 0u;
}

__global__ __launch_bounds__(256) void k_stats(
    const float* __restrict__ pred, const int* __restrict__ tgt,
    unsigned char* __restrict__ cls, unsigned* __restrict__ parent,
    Acc* __restrict__ acc)
{
  __shared__ float s_logpc[TB*C_];
  __shared__ float s_log1m[TB*C_];
  __shared__ float s_pred[TB*C_];
  __shared__ unsigned s_cnt[TB*C_];
  for (int i = threadIdx.x; i < TB*C_; i += blockDim.x) {
    s_logpc[i] = 0.f; s_log1m[i] = 0.f; s_pred[i] = 0.f; s_cnt[i] = 0u;
  }
  __syncthreads();
  int stride = gridDim.x * blockDim.x;
  for (int p = blockIdx.x * blockDim.x + threadIdx.x; p < NPIX; p += stride) {
    int b = p / HW_;
    int hw = p - b * HW_;
    const float* base = pred + (size_t)b * (C_*HW_) + hw;
    float best = base[0];
    int bc = 0;                         // first-max semantics == jnp.argmax
#pragma unroll
    for (int c = 1; c < C_; ++c) {
      float v = base[(size_t)c * HW_];
      if (v > best) { best = v; bc = c; }
    }
    cls[p] = (unsigned char)bc;
    parent[p] = bc ? (unsigned)p : INVAL;   // fused CCL init
    unsigned t = (unsigned)tgt[p];
    if (t >= TB) t = TB - 1;
    int slot = (int)t * C_ + bc;
    atomicAdd(&s_cnt[slot], 1u);
    if (bc) {
      float pc = fminf(fmaxf(best, 1e-7f), 1.0f - 1e-7f);
      atomicAdd(&s_pred[slot], best);
      atomicAdd(&s_logpc[slot], logf(pc));
      atomicAdd(&s_log1m[slot], log1pf(-pc));
    }
  }
  __syncthreads();
  for (int i = threadIdx.x; i < TB*C_; i += blockDim.x) {
    if (s_cnt[i]) atomicAdd(&(&acc->cnt[0][0])[i], s_cnt[i]);
    if (s_logpc[i] != 0.f)
      atomicAdd((unsigned long long*)&(&acc->f_logpc[0][0])[i],
                (unsigned long long)(long long)llrint((double)s_logpc[i] * FIX));
    if (s_log1m[i] != 0.f)
      atomicAdd((unsigned long long*)&(&acc->f_log1m[0][0])[i],
                (unsigned long long)(long long)llrint((double)s_log1m[i] * FIX));
    if (s_pred[i] != 0.f)
      atomicAdd((unsigned long long*)&(&acc->f_pred[0][0])[i],
                (unsigned long long)(long long)llrint((double)s_pred[i] * FIX));
  }
}

__global__ __launch_bounds__(256) void k_merge(const unsigned char* __restrict__ cls,
                                               unsigned* __restrict__ parent)
{
  unsigned p = blockIdx.x * blockDim.x + threadIdx.x;
  if (p >= NPIX) return;
  unsigned char c = cls[p];
  if (!c) return;
  unsigned hw = p % HW_;
  unsigned w = hw % W_;
  if (w + 1u < W_ && cls[p + 1] == c) unite(parent, p, p + 1);
  unsigned h = hw / W_;
  if (h + 1u < H_ && cls[p + W_] == c) unite(parent, p, p + W_);
}

__global__ __launch_bounds__(256) void k_count(const unsigned* __restrict__ parent,
                                               const unsigned char* __restrict__ cls,
                                               Acc* __restrict__ acc)
{
  __shared__ unsigned s[4];
  if (threadIdx.x < 4) s[threadIdx.x] = 0u;
  __syncthreads();
  int stride = gridDim.x * blockDim.x;
  for (int p = blockIdx.x * blockDim.x + threadIdx.x; p < NPIX; p += stride) {
    unsigned char c = cls[p];
    if (c && parent[p] == (unsigned)p) atomicAdd(&s[c - 1], 1u);
  }
  __syncthreads();
  if (threadIdx.x < 4 && s[threadIdx.x]) atomicAdd(&acc->ncomp[threadIdx.x], s[threadIdx.x]);
}

__global__ void k_final(const Acc* __restrict__ acc, const int* __restrict__ ntcp,
                        float* __restrict__ out)
{
  if (threadIdx.x || blockIdx.x) return;
  int NT = ntcp[0];
  if (NT < 1) NT = 1;
  if (NT > TB) NT = TB;

  double logpc[TB][C_], log1m[TB][C_], spred[TB][C_], cnt[TB][C_];
  unsigned cnti[TB][C_];
  for (int t = 0; t < TB; ++t)
    for (int c = 0; c < C_; ++c) {
      cnti[t][c]  = acc->cnt[t][c];
      cnt[t][c]   = (double)cnti[t][c];
      logpc[t][c] = (double)acc->f_logpc[t][c] / FIX;
      log1m[t][c] = (double)acc->f_log1m[t][c] / FIX;
      spred[t][c] = (double)acc->f_pred[t][c] / FIX;
    }
  unsigned ctot[C_];
  for (int c = 0; c < C_; ++c) {
    unsigned s = 0;
    for (int t = 0; t < TB; ++t) s += cnti[t][c];
    ctot[c] = s;
  }
  unsigned ncomp[C_] = {0, 0, 0, 0, 0};
  for (int v = 1; v < C_; ++v) ncomp[v] = acc->ncomp[v - 1];

  // ph value per predicted class: exact f32 replay of the reference fold,
  // including int32-wrap of n_comp*last_i and f32 cast/add order.
  float ph_tab[C_];
  for (int cc = 0; cc < C_; ++cc) {
    float ph = 0.0f;
    int li = 1;
    for (int v = 1; v < C_; ++v) {
      if (ctot[v] > 0) {                                       // present
        int prod = (int)((unsigned)ncomp[v] * (unsigned)li);   // int32 wrap
        float sv = (float)prod;
        float inc = ((cc == v) ? 1.0f : 0.0f) + sv;            // cur + scalar
        ph = ph + inc;                                         // ph += inc
        li = li + (int)ncomp[v] + ((ctot[v] < (unsigned)NPIX) ? 1 : 0);
      }
    }
    ph_tab[cc] = ph;
  }

  const float EPSF = 1e-7f;
  const double L1 = (double)logf(1.0f - EPSF);      // log(clip(1))
  const double M1 = (double)log1pf(-(1.0f - EPSF)); // log1p(-clip(1))
  const double L0 = (double)logf(EPSF);             // log(clip(0))
  const double M0 = (double)log1pf(-EPSF);          // log1p(-clip(0))
  const double N = (double)NPIX;

  // term 0: bce_dice(pred==0, tm==0) from counts
  double nt0 = 0; for (int c = 0; c < C_; ++c) nt0 += cnt[0][c];
  double np1 = (double)ctot[0];
  double n11 = cnt[0][0];
  double res = -(n11*L1 + (nt0 - n11)*L0 + (np1 - n11)*M1 + (N - nt0 - np1 + n11)*M0) / N
               + 1.0 - (2.0*n11 + 1.0) / (np1 + nt0 + 1.0);

  for (int t = 1; t < NT; ++t) {
    double ntt = 0; long long ntti = 0;
    for (int c = 0; c < C_; ++c) { ntt += cnt[t][c]; ntti += (long long)cnti[t][c]; }
    if (ntti == 0) continue;                        // present == False
    // median of ph over target-t pixels via 5-bin histogram
    int idx[C_] = {0, 1, 2, 3, 4};
    for (int i = 1; i < C_; ++i)
      for (int j = i; j > 0 && ph_tab[idx[j]] < ph_tab[idx[j-1]]; --j) {
        int tmp = idx[j]; idx[j] = idx[j-1]; idx[j-1] = tmp;
      }
    long long k = (ntti - 1) / 2;
    float med = ph_tab[idx[C_ - 1]];
    long long cum = 0;
    for (int i = 0; i < C_; ++i) {
      cum += (long long)cnti[t][idx[i]];
      if (cum > k) { med = ph_tab[idx[i]]; break; }
    }
    // p = pho * (ph==med): nonzero exactly for pred classes c>=1 with ph_tab[c]==med
    double A = 0, Bt = 0, inter = 0, sum_p = 0, ex = 0, nfg_t = 0, nfg_all = 0;
    for (int c = 1; c < C_; ++c) {
      if (ph_tab[c] == med) {
        A += logpc[t][c];
        inter += spred[t][c];
        nfg_t += cnt[t][c];
        for (int t2 = 0; t2 < TB; ++t2) {
          nfg_all += cnt[t2][c];
          sum_p += spred[t2][c];
          if (t2 != t) Bt += log1m[t2][c];
        }
      } else {
        ex += spred[t][c];   // (ph != med) & target: pho contribution
      }
    }
    double bce  = -(A + Bt + (ntt - nfg_t)*L0 + (N - ntt - (nfg_all - nfg_t))*M0) / N;
    double dice = 1.0 - (2.0*inter + 1.0) / (sum_p + ntt + 1.0);
    res += bce + dice + ex / ntt;
  }

  int nun = 0;
  for (int t = 0; t < NT; ++t) {
    long long s = 0;
    for (int c = 0; c < C_; ++c) s += (long long)cnti[t][c];
    if (s) nun++;
  }
  out[0] = (float)(res / (double)(2 * nun + 1));
}

extern "C" void kernel_launch(void* const* d_in, const int* in_sizes, int n_in,
                              void* d_out, int out_size, void* d_ws, size_t ws_size,
                              hipStream_t stream) {
  const float* pred = (const float*)d_in[0];
  const int* tgt = (const int*)d_in[1];
  const int* ntc = (const int*)d_in[2];
  float* out = (float*)d_out;
  char* ws = (char*)d_ws;
  // ws layout: parent u32[NPIX] | cls u8[NPIX] | Acc  (23.6 MB total)
  unsigned* parent = (unsigned*)ws;
  unsigned char* cls = (unsigned char*)(ws + (size_t)NPIX * 4);
  Acc* acc = (Acc*)(ws + (size_t)NPIX * 5);

  hipLaunchKernelGGL(k_zero, dim3(1), dim3(256), 0, stream, acc);
  hipLaunchKernelGGL(k_stats, dim3(1024), dim3(256), 0, stream, pred, tgt, cls, parent, acc);
  hipLaunchKernelGGL(k_merge, dim3(NPIX / 256), dim3(256), 0, stream, cls, parent);
  hipLaunchKernelGGL(k_count, dim3(1024), dim3(256), 0, stream, parent, cls, acc);
  hipLaunchKernelGGL(k_final, dim3(1), dim3(1), 0, stream, acc, ntc, out);
}

// Round 2
// 268.185 us; speedup vs baseline: 1.1230x; 1.1230x over previous
//
#include <hip/hip_runtime.h>
#include <stdint.h>
#include <math.h>

// pred_out [8,5,768,768] f32, target_mask [8,1,768,768] i32 (0..3), num_target_classes=4.
#define B_ 8
#define C_ 5
#define H_ 768
#define W_ 768
#define HW_ (H_*W_)
#define NPIX (B_*HW_)          // 4,718,592
#define NQUAD (NPIX/4)
#define TB 8
#define INVAL 0xFFFFFFFFu
#define FIX 16777216.0
#define LN2F 0.69314718056f
#define TILE 64
#define TPR (W_/TILE)          // 12 tiles per row
#define TPC (H_/TILE)          // 12 tiles per col
#define NTILES (B_*TPR*TPC)    // 1152
// boundary-merge candidates: 11 seam rows * 768 cols + 11 seam cols * 768 rows, per image
#define SEAMS_PER_IMG (11*768)
#define NB_HALF (B_*SEAMS_PER_IMG)   // 67584
#define NB_TOT (2*NB_HALF)           // 135168

struct Acc {
  long long f_logpc[TB][C_];
  long long f_log1m[TB][C_];
  long long f_pred [TB][C_];
  unsigned  cnt[TB][C_];
  unsigned  ncomp[8];
};

// ---------------- global union-find (lock-free, agent scope) ----------------
static __device__ __forceinline__ unsigned pload(const unsigned* P, unsigned i) {
  return __hip_atomic_load(&P[i], __ATOMIC_RELAXED, __HIP_MEMORY_SCOPE_AGENT);
}
static __device__ unsigned findRootG(unsigned* P, unsigned i) {
  unsigned p = pload(P, i);
  if (p == i) return i;
  unsigned gp = pload(P, p);
  while (p != gp) {
    // path halving: parents only decrease, so this preserves the forest invariant
    __hip_atomic_store(&P[i], gp, __ATOMIC_RELAXED, __HIP_MEMORY_SCOPE_AGENT);
    i = p; p = gp; gp = pload(P, p);
  }
  return p;
}
static __device__ void uniteG(unsigned* P, unsigned a, unsigned b) {
  a = findRootG(P, a);
  b = findRootG(P, b);
  while (a != b) {
    if (a < b) { unsigned t = a; a = b; b = t; }   // link larger -> smaller
    unsigned old = atomicCAS(&P[a], a, b);
    if (old == a) return;
    a = findRootG(P, old);
    b = findRootG(P, b);
  }
}
// ---------------- LDS union-find (workgroup scope) ----------------
static __device__ __forceinline__ unsigned ploadL(const unsigned* P, unsigned i) {
  return __hip_atomic_load(&P[i], __ATOMIC_RELAXED, __HIP_MEMORY_SCOPE_WORKGROUP);
}
static __device__ unsigned findRootL(const unsigned* P, unsigned i) {
  unsigned p = ploadL(P, i);
  while (p != i) { i = p; p = ploadL(P, i); }
  return i;
}
static __device__ void uniteL(unsigned* P, unsigned a, unsigned b) {
  a = findRootL(P, a);
  b = findRootL(P, b);
  while (a != b) {
    if (a < b) { unsigned t = a; a = b; b = t; }
    unsigned old = atomicCAS(&P[a], a, b);
    if (old == a) return;
    a = findRootL(P, old);
    b = findRootL(P, b);
  }
}

// ---------------- kernels ----------------
__global__ void k_zero(Acc* acc) {
  unsigned* p = (unsigned*)acc;
  int n = (int)(sizeof(Acc) / sizeof(unsigned));
  for (int i = threadIdx.x; i < n; i += blockDim.x) p[i] = 0u;
}

__global__ __launch_bounds__(256) void k_stats(
    const float4* __restrict__ pred, const int4* __restrict__ tgt,
    unsigned* __restrict__ cls4, Acc* __restrict__ acc)
{
  __shared__ float s_logpc[4][TB*C_];
  __shared__ float s_log1m[4][TB*C_];
  __shared__ float s_pred[4][TB*C_];
  __shared__ unsigned s_cnt[4][TB*C_];
  for (int i = threadIdx.x; i < 4*TB*C_; i += blockDim.x) {
    (&s_logpc[0][0])[i] = 0.f; (&s_log1m[0][0])[i] = 0.f;
    (&s_pred[0][0])[i] = 0.f;  (&s_cnt[0][0])[i] = 0u;
  }
  __syncthreads();
  const int w = threadIdx.x >> 6;
  const int stride = gridDim.x * blockDim.x;
  for (int q = blockIdx.x * blockDim.x + threadIdx.x; q < NQUAD; q += stride) {
    int b = q / (HW_/4);
    int hwq = q - b * (HW_/4);
    const float4* base = pred + (size_t)b * (C_*HW_/4) + hwq;
    float4 p0 = base[0];
    float4 p1 = base[HW_/4];
    float4 p2 = base[2*(HW_/4)];
    float4 p3 = base[3*(HW_/4)];
    float4 p4 = base[4*(HW_/4)];
    int4 t4 = tgt[q];
    unsigned packed = 0;
#define DOPIX(J, V0, V1, V2, V3, V4, T)                                        \
    {                                                                          \
      float best = (V0); int bc = 0;                                           \
      if ((V1) > best) { best = (V1); bc = 1; }                                \
      if ((V2) > best) { best = (V2); bc = 2; }                                \
      if ((V3) > best) { best = (V3); bc = 3; }                                \
      if ((V4) > best) { best = (V4); bc = 4; }                                \
      unsigned tt = (unsigned)(T); if (tt >= TB) tt = TB - 1;                  \
      int slot = (int)tt * C_ + bc;                                            \
      atomicAdd(&s_cnt[w][slot], 1u);                                          \
      if (bc) {                                                                \
        float pc = fminf(fmaxf(best, 1e-7f), 1.0f - 1e-7f);                    \
        atomicAdd(&s_pred[w][slot], best);                                     \
        atomicAdd(&s_logpc[w][slot], __log2f(pc) * LN2F);                      \
        atomicAdd(&s_log1m[w][slot], __log2f(1.0f - pc) * LN2F);               \
      }                                                                        \
      packed |= ((unsigned)bc) << (8 * (J));                                   \
    }
    DOPIX(0, p0.x, p1.x, p2.x, p3.x, p4.x, t4.x)
    DOPIX(1, p0.y, p1.y, p2.y, p3.y, p4.y, t4.y)
    DOPIX(2, p0.z, p1.z, p2.z, p3.z, p4.z, t4.z)
    DOPIX(3, p0.w, p1.w, p2.w, p3.w, p4.w, t4.w)
#undef DOPIX
    cls4[q] = packed;
  }
  __syncthreads();
  for (int i = threadIdx.x; i < TB*C_; i += blockDim.x) {
    unsigned c = s_cnt[0][i] + s_cnt[1][i] + s_cnt[2][i] + s_cnt[3][i];
    if (c) atomicAdd(&(&acc->cnt[0][0])[i], c);
    double vp = (double)s_pred[0][i] + s_pred[1][i] + s_pred[2][i] + s_pred[3][i];
    double vl = (double)s_logpc[0][i] + s_logpc[1][i] + s_logpc[2][i] + s_logpc[3][i];
    double vm = (double)s_log1m[0][i] + s_log1m[1][i] + s_log1m[2][i] + s_log1m[3][i];
    if (vp != 0.0)
      atomicAdd((unsigned long long*)&(&acc->f_pred[0][0])[i],
                (unsigned long long)(long long)llrint(vp * FIX));
    if (vl != 0.0)
      atomicAdd((unsigned long long*)&(&acc->f_logpc[0][0])[i],
                (unsigned long long)(long long)llrint(vl * FIX));
    if (vm != 0.0)
      atomicAdd((unsigned long long*)&(&acc->f_log1m[0][0])[i],
                (unsigned long long)(long long)llrint(vm * FIX));
  }
}

// Pass A: per-tile (64x64) union-find entirely in LDS; write flattened global parents.
__global__ __launch_bounds__(256) void k_ccl_local(const unsigned char* __restrict__ cls,
                                                   unsigned* __restrict__ parent)
{
  __shared__ unsigned lab[TILE*TILE];
  __shared__ unsigned lclsw[TILE*TILE/4];
  unsigned char* lcls = (unsigned char*)lclsw;
  int blk = blockIdx.x;
  int b = blk / (TPR*TPC);
  int rem = blk - b * (TPR*TPC);
  int ty0 = (rem / TPR) * TILE;
  int tx0 = (rem - (rem / TPR) * TPR) * TILE;
  const unsigned char* cbase = cls + (size_t)b * HW_;
  // load tile cls (uchar4 per thread x4) + init labels
#pragma unroll
  for (int it = 0; it < 4; ++it) {
    int li = (threadIdx.x + it * 256) * 4;
    int ty = li >> 6, tx = li & 63;
    lclsw[li >> 2] = *(const unsigned*)(cbase + (size_t)(ty0 + ty) * W_ + tx0 + tx);
  }
  __syncthreads();
#pragma unroll
  for (int it = 0; it < 16; ++it) {
    int li = threadIdx.x + it * 256;
    lab[li] = lcls[li] ? (unsigned)li : INVAL;
  }
  __syncthreads();
  // local unions (right + down, in-tile)
#pragma unroll
  for (int it = 0; it < 16; ++it) {
    int li = threadIdx.x + it * 256;
    unsigned char c = lcls[li];
    if (!c) continue;
    int tx = li & 63, ty = li >> 6;
    if (tx < 63 && lcls[li + 1] == c)  uniteL(lab, li, li + 1);
    if (ty < 63 && lcls[li + 64] == c) uniteL(lab, li, li + 64);
  }
  __syncthreads();
  // flatten + write global parent (depth <= 1 afterwards)
#pragma unroll
  for (int it = 0; it < 16; ++it) {
    int li = threadIdx.x + it * 256;
    int ty = li >> 6, tx = li & 63;
    unsigned g = (unsigned)(b * HW_ + (ty0 + ty) * W_ + tx0 + tx);
    unsigned val = INVAL;
    if (lcls[li]) {
      unsigned r = findRootL(lab, li);
      val = (unsigned)(b * HW_ + (ty0 + (int)(r >> 6)) * W_ + tx0 + (int)(r & 63));
    }
    parent[g] = val;
  }
}

// Pass B: merge across tile seams only (~135k candidate edges).
__global__ __launch_bounds__(256) void k_merge_bound(const unsigned char* __restrict__ cls,
                                                     unsigned* __restrict__ parent)
{
  int idx = blockIdx.x * blockDim.x + threadIdx.x;
  if (idx >= NB_TOT) return;
  unsigned p, q;
  if (idx < NB_HALF) {             // down edges across seam rows h = r*64+63
    int b = idx / SEAMS_PER_IMG;
    int r2 = idx - b * SEAMS_PER_IMG;
    int rrow = r2 / W_;
    int col = r2 - rrow * W_;
    int h = rrow * TILE + (TILE - 1);
    p = (unsigned)(b * HW_ + h * W_ + col);
    q = p + W_;
  } else {                         // right edges across seam cols w = r*64+63
    int i2 = idx - NB_HALF;
    int b = i2 / SEAMS_PER_IMG;
    int r2 = i2 - b * SEAMS_PER_IMG;
    int rcol = r2 / H_;
    int row = r2 - rcol * H_;
    int ww = rcol * TILE + (TILE - 1);
    p = (unsigned)(b * HW_ + row * W_ + ww);
    q = p + 1;
  }
  unsigned char c = cls[p];
  if (c && cls[q] == c) uniteG(parent, p, q);
}

__global__ __launch_bounds__(256) void k_count(const uint4* __restrict__ parent4,
                                               const unsigned* __restrict__ cls4,
                                               Acc* __restrict__ acc)
{
  __shared__ unsigned s[4];
  if (threadIdx.x < 4) s[threadIdx.x] = 0u;
  __syncthreads();
  unsigned c0 = 0, c1 = 0, c2 = 0, c3 = 0;
  int stride = gridDim.x * blockDim.x;
  for (int q = blockIdx.x * blockDim.x + threadIdx.x; q < NQUAD; q += stride) {
    uint4 par = parent4[q];
    unsigned cw = cls4[q];
    unsigned pix = (unsigned)q * 4u;
#define CK(J, PR)                                                              \
    {                                                                          \
      unsigned c = (cw >> (8*(J))) & 255u;                                     \
      if (c && (PR) == pix + (J)) {                                            \
        if (c == 1) c0++; else if (c == 2) c1++; else if (c == 3) c2++; else c3++; \
      }                                                                        \
    }
    CK(0, par.x) CK(1, par.y) CK(2, par.z) CK(3, par.w)
#undef CK
  }
  if (c0) atomicAdd(&s[0], c0);
  if (c1) atomicAdd(&s[1], c1);
  if (c2) atomicAdd(&s[2], c2);
  if (c3) atomicAdd(&s[3], c3);
  __syncthreads();
  if (threadIdx.x < 4 && s[threadIdx.x]) atomicAdd(&acc->ncomp[threadIdx.x], s[threadIdx.x]);
}

__global__ void k_final(const Acc* __restrict__ acc, const int* __restrict__ ntcp,
                        float* __restrict__ out)
{
  if (threadIdx.x || blockIdx.x) return;
  int NT = ntcp[0];
  if (NT < 1) NT = 1;
  if (NT > TB) NT = TB;

  double logpc[TB][C_], log1m[TB][C_], spred[TB][C_], cnt[TB][C_];
  unsigned cnti[TB][C_];
  for (int t = 0; t < TB; ++t)
    for (int c = 0; c < C_; ++c) {
      cnti[t][c]  = acc->cnt[t][c];
      cnt[t][c]   = (double)cnti[t][c];
      logpc[t][c] = (double)acc->f_logpc[t][c] / FIX;
      log1m[t][c] = (double)acc->f_log1m[t][c] / FIX;
      spred[t][c] = (double)acc->f_pred[t][c] / FIX;
    }
  unsigned ctot[C_];
  for (int c = 0; c < C_; ++c) {
    unsigned s = 0;
    for (int t = 0; t < TB; ++t) s += cnti[t][c];
    ctot[c] = s;
  }
  unsigned ncomp[C_] = {0, 0, 0, 0, 0};
  for (int v = 1; v < C_; ++v) ncomp[v] = acc->ncomp[v - 1];

  // ph per predicted class: exact f32 replay incl. int32 wrap of n_comp*last_i
  float ph_tab[C_];
  for (int cc = 0; cc < C_; ++cc) {
    float ph = 0.0f;
    int li = 1;
    for (int v = 1; v < C_; ++v) {
      if (ctot[v] > 0) {
        int prod = (int)((unsigned)ncomp[v] * (unsigned)li);
        float sv = (float)prod;
        float inc = ((cc == v) ? 1.0f : 0.0f) + sv;
        ph = ph + inc;
        li = li + (int)ncomp[v] + ((ctot[v] < (unsigned)NPIX) ? 1 : 0);
      }
    }
    ph_tab[cc] = ph;
  }

  const float EPSF = 1e-7f;
  const double L1 = (double)logf(1.0f - EPSF);
  const double M1 = (double)log1pf(-(1.0f - EPSF));
  const double L0 = (double)logf(EPSF);
  const double M0 = (double)log1pf(-EPSF);
  const double N = (double)NPIX;

  double nt0 = 0; for (int c = 0; c < C_; ++c) nt0 += cnt[0][c];
  double np1 = (double)ctot[0];
  double n11 = cnt[0][0];
  double res = -(n11*L1 + (nt0 - n11)*L0 + (np1 - n11)*M1 + (N - nt0 - np1 + n11)*M0) / N
               + 1.0 - (2.0*n11 + 1.0) / (np1 + nt0 + 1.0);

  for (int t = 1; t < NT; ++t) {
    double ntt = 0; long long ntti = 0;
    for (int c = 0; c < C_; ++c) { ntt += cnt[t][c]; ntti += (long long)cnti[t][c]; }
    if (ntti == 0) continue;
    int idx[C_] = {0, 1, 2, 3, 4};
    for (int i = 1; i < C_; ++i)
      for (int j = i; j > 0 && ph_tab[idx[j]] < ph_tab[idx[j-1]]; --j) {
        int tmp = idx[j]; idx[j] = idx[j-1]; idx[j-1] = tmp;
      }
    long long k = (ntti - 1) / 2;
    float med = ph_tab[idx[C_ - 1]];
    long long cum = 0;
    for (int i = 0; i < C_; ++i) {
      cum += (long long)cnti[t][idx[i]];
      if (cum > k) { med = ph_tab[idx[i]]; break; }
    }
    double A = 0, Bt = 0, inter = 0, sum_p = 0, ex = 0, nfg_t = 0, nfg_all = 0;
    for (int c = 1; c < C_; ++c) {
      if (ph_tab[c] == med) {
        A += logpc[t][c];
        inter += spred[t][c];
        nfg_t += cnt[t][c];
        for (int t2 = 0; t2 < TB; ++t2) {
          nfg_all += cnt[t2][c];
          sum_p += spred[t2][c];
          if (t2 != t) Bt += log1m[t2][c];
        }
      } else {
        ex += spred[t][c];
      }
    }
    double bce  = -(A + Bt + (ntt - nfg_t)*L0 + (N - ntt - (nfg_all - nfg_t))*M0) / N;
    double dice = 1.0 - (2.0*inter + 1.0) / (sum_p + ntt + 1.0);
    res += bce + dice + ex / ntt;
  }

  int nun = 0;
  for (int t = 0; t < NT; ++t) {
    long long s = 0;
    for (int c = 0; c < C_; ++c) s += (long long)cnti[t][c];
    if (s) nun++;
  }
  out[0] = (float)(res / (double)(2 * nun + 1));
}

extern "C" void kernel_launch(void* const* d_in, const int* in_sizes, int n_in,
                              void* d_out, int out_size, void* d_ws, size_t ws_size,
                              hipStream_t stream) {
  const float* pred = (const float*)d_in[0];
  const int* tgt = (const int*)d_in[1];
  const int* ntc = (const int*)d_in[2];
  float* out = (float*)d_out;
  char* ws = (char*)d_ws;
  // ws layout: parent u32[NPIX] | cls u8[NPIX] | Acc  (23.6 MB)
  unsigned* parent = (unsigned*)ws;
  unsigned char* cls = (unsigned char*)(ws + (size_t)NPIX * 4);
  Acc* acc = (Acc*)(ws + (size_t)NPIX * 5);

  hipLaunchKernelGGL(k_zero, dim3(1), dim3(256), 0, stream, acc);
  hipLaunchKernelGGL(k_stats, dim3(2048), dim3(256), 0, stream,
                     (const float4*)pred, (const int4*)tgt, (unsigned*)cls, acc);
  hipLaunchKernelGGL(k_ccl_local, dim3(NTILES), dim3(256), 0, stream, cls, parent);
  hipLaunchKernelGGL(k_merge_bound, dim3((NB_TOT + 255) / 256), dim3(256), 0, stream, cls, parent);
  hipLaunchKernelGGL(k_count, dim3(1024), dim3(256), 0, stream,
                     (const uint4*)parent, (const unsigned*)cls, acc);
  hipLaunchKernelGGL(k_final, dim3(1), dim3(1), 0, stream, acc, ntc, out);
}